// Round 2
// baseline (1045.561 us; speedup 1.0000x reference)
//
#include <hip/hip_runtime.h>
#include <math.h>

#define FDIM 128
#define F3   384

static constexpr int K1_R = 16;   // rows per block, context net
static constexpr int K2_R = 16;   // rows per block, v@Wmix ctx
static constexpr int K4_R = 8;    // rows per block, epilogue
static constexpr int CHUNK = 64;  // edges per LDS prefetch chunk in k3

// ---------------------------------------------------------------------------
// Kernel 1: X = silu(H @ W1 + b1) @ W2 + b2        [N, 3F]
// thread = output channel f, K1_R atoms per block; a-loops unrolled x8 so
// weight loads batch (8-24 outstanding) instead of one L2 load per 16 FMAs.
// ---------------------------------------------------------------------------
__global__ __launch_bounds__(128) void k1_ctxnet(
    const float* __restrict__ H,  const float* __restrict__ W1,
    const float* __restrict__ b1, const float* __restrict__ W2,
    const float* __restrict__ b2, float* __restrict__ X, int N)
{
    __shared__ float sH[K1_R][FDIM];
    __shared__ float sT[K1_R][FDIM];
    const int f  = threadIdx.x;
    const int n0 = blockIdx.x * K1_R;

    for (int r = 0; r < K1_R; ++r) {
        int n = n0 + r;
        sH[r][f] = (n < N) ? H[(size_t)n * FDIM + f] : 0.f;
    }
    __syncthreads();

    float acc[K1_R];
    #pragma unroll
    for (int r = 0; r < K1_R; ++r) acc[r] = 0.f;
    #pragma unroll 8
    for (int a = 0; a < FDIM; ++a) {
        float w = W1[a * FDIM + f];
        #pragma unroll
        for (int r = 0; r < K1_R; ++r) acc[r] = fmaf(sH[r][a], w, acc[r]);
    }
    float bb = b1[f];
    #pragma unroll
    for (int r = 0; r < K1_R; ++r) {
        float t = acc[r] + bb;
        sT[r][f] = t / (1.f + expf(-t));   // silu
    }
    __syncthreads();

    float a0[K1_R], a1[K1_R], a2[K1_R];
    #pragma unroll
    for (int r = 0; r < K1_R; ++r) { a0[r] = 0.f; a1[r] = 0.f; a2[r] = 0.f; }
    #pragma unroll 8
    for (int a = 0; a < FDIM; ++a) {
        float w0 = W2[a * F3 + f];
        float w1 = W2[a * F3 + FDIM + f];
        float w2 = W2[a * F3 + 2 * FDIM + f];
        #pragma unroll
        for (int r = 0; r < K1_R; ++r) {
            float t = sT[r][a];
            a0[r] = fmaf(t, w0, a0[r]);
            a1[r] = fmaf(t, w1, a1[r]);
            a2[r] = fmaf(t, w2, a2[r]);
        }
    }
    float c0 = b2[f], c1 = b2[FDIM + f], c2 = b2[2 * FDIM + f];
    for (int r = 0; r < K1_R; ++r) {
        int n = n0 + r;
        if (n < N) {
            X[(size_t)n * F3 + f]            = a0[r] + c0;
            X[(size_t)n * F3 + FDIM + f]     = a1[r] + c1;
            X[(size_t)n * F3 + 2 * FDIM + f] = a2[r] + c2;
        }
    }
}

// ---------------------------------------------------------------------------
// Kernel 2: ctx[n,f] = sum_d (v[n,d,:] @ Wmix[:, f]) * (v[n,d,:] @ Wmix[:, F+f])
// ---------------------------------------------------------------------------
__global__ __launch_bounds__(128) void k2_ctx(
    const float* __restrict__ v, const float* __restrict__ Wmix,
    float* __restrict__ ctx, int N)
{
    __shared__ float sv[3][K2_R][FDIM];
    const int f  = threadIdx.x;
    const int n0 = blockIdx.x * K2_R;

    for (int r = 0; r < K2_R; ++r) {
        int n = n0 + r;
        for (int d = 0; d < 3; ++d)
            sv[d][r][f] = (n < N) ? v[((size_t)n * 3 + d) * FDIM + f] : 0.f;
    }
    __syncthreads();

    float cacc[K2_R];
    #pragma unroll
    for (int r = 0; r < K2_R; ++r) cacc[r] = 0.f;

    for (int d = 0; d < 3; ++d) {
        float aV[K2_R], aW[K2_R];
        #pragma unroll
        for (int r = 0; r < K2_R; ++r) { aV[r] = 0.f; aW[r] = 0.f; }
        #pragma unroll 8
        for (int a = 0; a < FDIM; ++a) {
            float w0 = Wmix[a * (2 * FDIM) + f];
            float w1 = Wmix[a * (2 * FDIM) + FDIM + f];
            #pragma unroll
            for (int r = 0; r < K2_R; ++r) {
                float t = sv[d][r][a];
                aV[r] = fmaf(t, w0, aV[r]);
                aW[r] = fmaf(t, w1, aW[r]);
            }
        }
        #pragma unroll
        for (int r = 0; r < K2_R; ++r) cacc[r] = fmaf(aV[r], aW[r], cacc[r]);
    }
    for (int r = 0; r < K2_R; ++r) {
        int n = n0 + r;
        if (n < N) ctx[(size_t)n * FDIM + f] = cacc[r];
    }
}

// ---------------------------------------------------------------------------
// Kernel 3: edge gather + segment reduction. idx_i SORTED -> block per atom.
// 256 threads = two 128-lane halves over interleaved edges; idx_j/dir are
// LDS-prefetched per 64-edge chunk (kills the idx->gather dependent chain);
// edge loop pair-unrolled so each half keeps 18 loads in flight.
// ---------------------------------------------------------------------------
__device__ inline int lower_bound_i(const int* __restrict__ a, int n, int val) {
    int lo = 0, hi = n;
    while (lo < hi) {
        int m = (lo + hi) >> 1;
        if (a[m] < val) lo = m + 1; else hi = m;
    }
    return lo;
}

__global__ __launch_bounds__(256) void k3_edges(
    const float* __restrict__ X, const float* __restrict__ V,
    const float* __restrict__ Wij, const float* __restrict__ dir_ij,
    const int* __restrict__ idx_i, const int* __restrict__ idx_j,
    float* __restrict__ dh, float* __restrict__ dv, int E)
{
    const int n    = blockIdx.x;
    const int tid  = threadIdx.x;
    const int f    = tid & 127;
    const int half = tid >> 7;

    __shared__ int   sj[CHUNK];
    __shared__ float sd[CHUNK][4];
    __shared__ float sacc[4][FDIM];

    const int e0 = lower_bound_i(idx_i, E, n);
    const int e1 = lower_bound_i(idx_i, E, n + 1);

    float adh = 0.f, a0 = 0.f, a1 = 0.f, a2 = 0.f;

    for (int base = e0; base < e1; base += CHUNK) {
        const int cnt = (e1 - base < CHUNK) ? (e1 - base) : CHUNK;
        if (tid < cnt) sj[tid] = idx_j[base + tid];
        for (int t = tid; t < 3 * cnt; t += 256)
            sd[t / 3][t % 3] = dir_ij[(size_t)base * 3 + t];
        __syncthreads();

        int k = half;
        for (; k + 2 < cnt; k += 4) {
            const int eA = base + k, eB = base + k + 2;
            const int jA = sj[k],    jB = sj[k + 2];
            const float* wA = Wij + (size_t)eA * F3;
            const float* wB = Wij + (size_t)eB * F3;
            const float* xA = X + (size_t)jA * F3;
            const float* xB = X + (size_t)jB * F3;
            const float* vA = V + (size_t)jA * F3;
            const float* vB = V + (size_t)jB * F3;
            float wA0 = wA[f], wA1 = wA[FDIM + f], wA2 = wA[2 * FDIM + f];
            float xA0 = xA[f], xA1 = xA[FDIM + f], xA2 = xA[2 * FDIM + f];
            float vA0 = vA[f], vA1 = vA[FDIM + f], vA2 = vA[2 * FDIM + f];
            float wB0 = wB[f], wB1 = wB[FDIM + f], wB2 = wB[2 * FDIM + f];
            float xB0 = xB[f], xB1 = xB[FDIM + f], xB2 = xB[2 * FDIM + f];
            float vB0 = vB[f], vB1 = vB[FDIM + f], vB2 = vB[2 * FDIM + f];
            float dA0 = sd[k][0],     dA1 = sd[k][1],     dA2 = sd[k][2];
            float dB0 = sd[k + 2][0], dB1 = sd[k + 2][1], dB2 = sd[k + 2][2];

            adh = fmaf(wA0, xA0, adh);
            float rA = wA1 * xA1, sA = wA2 * xA2;
            a0 = fmaf(rA, dA0, fmaf(sA, vA0, a0));
            a1 = fmaf(rA, dA1, fmaf(sA, vA1, a1));
            a2 = fmaf(rA, dA2, fmaf(sA, vA2, a2));

            adh = fmaf(wB0, xB0, adh);
            float rB = wB1 * xB1, sB = wB2 * xB2;
            a0 = fmaf(rB, dB0, fmaf(sB, vB0, a0));
            a1 = fmaf(rB, dB1, fmaf(sB, vB1, a1));
            a2 = fmaf(rB, dB2, fmaf(sB, vB2, a2));
        }
        for (; k < cnt; k += 2) {
            const int e = base + k;
            const int j = sj[k];
            const float* w = Wij + (size_t)e * F3;
            const float* x = X + (size_t)j * F3;
            const float* vv = V + (size_t)j * F3;
            float w0 = w[f], w1 = w[FDIM + f], w2 = w[2 * FDIM + f];
            float x0 = x[f], x1 = x[FDIM + f], x2 = x[2 * FDIM + f];
            float v0 = vv[f], v1 = vv[FDIM + f], v2 = vv[2 * FDIM + f];
            float d0 = sd[k][0], d1 = sd[k][1], d2 = sd[k][2];
            adh = fmaf(w0, x0, adh);
            float r = w1 * x1, s = w2 * x2;
            a0 = fmaf(r, d0, fmaf(s, v0, a0));
            a1 = fmaf(r, d1, fmaf(s, v1, a1));
            a2 = fmaf(r, d2, fmaf(s, v2, a2));
        }
        __syncthreads();
    }

    if (half == 1) {
        sacc[0][f] = adh; sacc[1][f] = a0; sacc[2][f] = a1; sacc[3][f] = a2;
    }
    __syncthreads();
    if (half == 0) {
        adh += sacc[0][f]; a0 += sacc[1][f]; a1 += sacc[2][f]; a2 += sacc[3][f];
        dh[(size_t)n * FDIM + f]          = adh;
        dv[(size_t)n * F3 + f]            = a0;
        dv[(size_t)n * F3 + FDIM + f]     = a1;
        dv[(size_t)n * F3 + 2 * FDIM + f] = a2;
    }
}

// ---------------------------------------------------------------------------
// Kernel 4: epilogue.
// q  = LN(h + dh@Whr + (dh@Whf)*ctx) * gamma + beta
// mu = (v*(1+dh.Wvr) + dv) / rms
// ---------------------------------------------------------------------------
__device__ inline float block_reduce_sum_128(float val, float* tmp) {
    #pragma unroll
    for (int o = 32; o > 0; o >>= 1) val += __shfl_down(val, o, 64);
    const int tid = threadIdx.x;
    if ((tid & 63) == 0) tmp[tid >> 6] = val;
    __syncthreads();
    float r = tmp[0] + tmp[1];
    __syncthreads();
    return r;
}

__global__ __launch_bounds__(128) void k4_epilogue(
    const float* __restrict__ h,   const float* __restrict__ v,
    const float* __restrict__ dh,  const float* __restrict__ dv,
    const float* __restrict__ ctx,
    const float* __restrict__ Whr, const float* __restrict__ Whf,
    const float* __restrict__ Wvr,
    const float* __restrict__ gamma, const float* __restrict__ beta,
    float* __restrict__ q, float* __restrict__ mu, int N)
{
    __shared__ float sdh[K4_R][FDIM];
    __shared__ float sred[2];
    const int f  = threadIdx.x;
    const int n0 = blockIdx.x * K4_R;

    for (int r = 0; r < K4_R; ++r) {
        int n = n0 + r;
        sdh[r][f] = (n < N) ? dh[(size_t)n * FDIM + f] : 0.f;
    }
    __syncthreads();

    float accR[K4_R], accF[K4_R];
    #pragma unroll
    for (int r = 0; r < K4_R; ++r) { accR[r] = 0.f; accF[r] = 0.f; }
    #pragma unroll 8
    for (int a = 0; a < FDIM; ++a) {
        float wr = Whr[a * FDIM + f];
        float wf = Whf[a * FDIM + f];
        #pragma unroll
        for (int r = 0; r < K4_R; ++r) {
            accR[r] = fmaf(sdh[r][a], wr, accR[r]);
            accF[r] = fmaf(sdh[r][a], wf, accF[r]);
        }
    }

    const float wv = Wvr[f];
    const float g  = gamma[f];
    const float bt = beta[f];

    for (int r = 0; r < K4_R; ++r) {
        int n = n0 + r;
        if (n >= N) break;   // uniform across block

        float s = block_reduce_sum_128(sdh[r][f] * wv, sred);

        float u    = h[(size_t)n * FDIM + f] + accR[r] + accF[r] * ctx[(size_t)n * FDIM + f];
        float mean = block_reduce_sum_128(u, sred) * (1.f / 128.f);
        float dlt  = u - mean;
        float var  = block_reduce_sum_128(dlt * dlt, sred) * (1.f / 128.f);
        q[(size_t)n * FDIM + f] = dlt * rsqrtf(var + 1e-5f) * g + bt;

        float sc = 1.f + s;
        float x0 = fmaf(v[((size_t)n * 3 + 0) * FDIM + f], sc, dv[(size_t)n * F3 + f]);
        float x1 = fmaf(v[((size_t)n * 3 + 1) * FDIM + f], sc, dv[(size_t)n * F3 + FDIM + f]);
        float x2 = fmaf(v[((size_t)n * 3 + 2) * FDIM + f], sc, dv[(size_t)n * F3 + 2 * FDIM + f]);
        float sq  = x0 * x0 + x1 * x1 + x2 * x2;
        float tot = block_reduce_sum_128(sq, sred) * (1.f / 128.f);
        float inv = rsqrtf(tot + 1e-8f);
        mu[((size_t)n * 3 + 0) * FDIM + f] = x0 * inv;
        mu[((size_t)n * 3 + 1) * FDIM + f] = x1 * inv;
        mu[((size_t)n * 3 + 2) * FDIM + f] = x2 * inv;
    }
}

// ---------------------------------------------------------------------------
extern "C" void kernel_launch(void* const* d_in, const int* in_sizes, int n_in,
                              void* d_out, int out_size, void* d_ws, size_t ws_size,
                              hipStream_t stream)
{
    const float* h     = (const float*)d_in[0];
    const float* v     = (const float*)d_in[1];
    const float* H     = (const float*)d_in[2];
    const float* V     = (const float*)d_in[3];
    const float* Wij   = (const float*)d_in[4];
    const float* dir   = (const float*)d_in[5];
    const float* W1    = (const float*)d_in[6];
    const float* b1    = (const float*)d_in[7];
    const float* W2    = (const float*)d_in[8];
    const float* b2    = (const float*)d_in[9];
    const float* Wmix  = (const float*)d_in[10];
    const float* Whr   = (const float*)d_in[11];
    const float* Whf   = (const float*)d_in[12];
    const float* Wvr   = (const float*)d_in[13];
    const float* gamma = (const float*)d_in[14];
    const float* beta  = (const float*)d_in[15];
    const int*   idx_i = (const int*)d_in[16];
    const int*   idx_j = (const int*)d_in[17];

    const int N = in_sizes[0] / FDIM;
    const int E = in_sizes[16];

    float* ws  = (float*)d_ws;
    float* X   = ws;                         // N*384
    float* ctx = X   + (size_t)N * F3;       // N*128
    float* dh  = ctx + (size_t)N * FDIM;     // N*128
    float* dv  = dh  + (size_t)N * FDIM;     // N*384

    float* q   = (float*)d_out;              // N*128
    float* mu  = q + (size_t)N * FDIM;       // N*384

    hipLaunchKernelGGL(k1_ctxnet, dim3((N + K1_R - 1) / K1_R), dim3(128), 0, stream,
                       H, W1, b1, W2, b2, X, N);
    hipLaunchKernelGGL(k2_ctx, dim3((N + K2_R - 1) / K2_R), dim3(128), 0, stream,
                       v, Wmix, ctx, N);
    hipLaunchKernelGGL(k3_edges, dim3(N), dim3(256), 0, stream,
                       X, V, Wij, dir, idx_i, idx_j, dh, dv, E);
    hipLaunchKernelGGL(k4_epilogue, dim3((N + K4_R - 1) / K4_R), dim3(128), 0, stream,
                       h, v, dh, dv, ctx, Whr, Whf, Wvr, gamma, beta, q, mu, N);
}

// Round 3
// 887.765 us; speedup vs baseline: 1.1777x; 1.1777x over previous
//
#include <hip/hip_runtime.h>
#include <math.h>

#define FDIM 128
#define F3   384

static constexpr int K1_R = 8;    // rows per block, context net
static constexpr int K2_R = 8;    // rows per block, v@Wmix ctx
static constexpr int K4_R = 4;    // rows per block, epilogue
static constexpr int CHUNK = 64;  // edges per LDS prefetch chunk in k3

// ---------------------------------------------------------------------------
// Kernel 0: segment offsets. seg[n] = lower_bound(idx_i, n), seg[N] = E.
// One binary search per thread, fully parallel (replaces 2 serialized
// searches at the head of every k3 block = ~36 dependent L2 loads x 10000).
// ---------------------------------------------------------------------------
__global__ __launch_bounds__(256) void k0_seg(
    const int* __restrict__ idx_i, int* __restrict__ seg, int E, int N)
{
    int n = blockIdx.x * 256 + threadIdx.x;
    if (n > N) return;
    if (n == N) { seg[n] = E; return; }
    int lo = 0, hi = E;
    while (lo < hi) {
        int m = (lo + hi) >> 1;
        if (idx_i[m] < n) lo = m + 1; else hi = m;
    }
    seg[n] = lo;
}

// ---------------------------------------------------------------------------
// Kernel 1: X = silu(H @ W1 + b1) @ W2 + b2        [N, 3F]
// K1_R=8 rows/block -> 1250 blocks (2.4 waves/SIMD). unroll 4 (unroll 8
// regressed: hoisted loads blew register pressure).
// ---------------------------------------------------------------------------
__global__ __launch_bounds__(128) void k1_ctxnet(
    const float* __restrict__ H,  const float* __restrict__ W1,
    const float* __restrict__ b1, const float* __restrict__ W2,
    const float* __restrict__ b2, float* __restrict__ X, int N)
{
    __shared__ float sH[K1_R][FDIM];
    __shared__ float sT[K1_R][FDIM];
    const int f  = threadIdx.x;
    const int n0 = blockIdx.x * K1_R;

    for (int r = 0; r < K1_R; ++r) {
        int n = n0 + r;
        sH[r][f] = (n < N) ? H[(size_t)n * FDIM + f] : 0.f;
    }
    __syncthreads();

    float acc[K1_R];
    #pragma unroll
    for (int r = 0; r < K1_R; ++r) acc[r] = 0.f;
    #pragma unroll 4
    for (int a = 0; a < FDIM; ++a) {
        float w = W1[a * FDIM + f];
        #pragma unroll
        for (int r = 0; r < K1_R; ++r) acc[r] = fmaf(sH[r][a], w, acc[r]);
    }
    float bb = b1[f];
    #pragma unroll
    for (int r = 0; r < K1_R; ++r) {
        float t = acc[r] + bb;
        sT[r][f] = t / (1.f + expf(-t));   // silu
    }
    __syncthreads();

    float a0[K1_R], a1[K1_R], a2[K1_R];
    #pragma unroll
    for (int r = 0; r < K1_R; ++r) { a0[r] = 0.f; a1[r] = 0.f; a2[r] = 0.f; }
    #pragma unroll 4
    for (int a = 0; a < FDIM; ++a) {
        float w0 = W2[a * F3 + f];
        float w1 = W2[a * F3 + FDIM + f];
        float w2 = W2[a * F3 + 2 * FDIM + f];
        #pragma unroll
        for (int r = 0; r < K1_R; ++r) {
            float t = sT[r][a];
            a0[r] = fmaf(t, w0, a0[r]);
            a1[r] = fmaf(t, w1, a1[r]);
            a2[r] = fmaf(t, w2, a2[r]);
        }
    }
    float c0 = b2[f], c1 = b2[FDIM + f], c2 = b2[2 * FDIM + f];
    for (int r = 0; r < K1_R; ++r) {
        int n = n0 + r;
        if (n < N) {
            X[(size_t)n * F3 + f]            = a0[r] + c0;
            X[(size_t)n * F3 + FDIM + f]     = a1[r] + c1;
            X[(size_t)n * F3 + 2 * FDIM + f] = a2[r] + c2;
        }
    }
}

// ---------------------------------------------------------------------------
// Kernel 2: ctx[n,f] = sum_d (v[n,d,:] @ Wmix[:, f]) * (v[n,d,:] @ Wmix[:, F+f])
// ---------------------------------------------------------------------------
__global__ __launch_bounds__(128) void k2_ctx(
    const float* __restrict__ v, const float* __restrict__ Wmix,
    float* __restrict__ ctx, int N)
{
    __shared__ float sv[3][K2_R][FDIM];
    const int f  = threadIdx.x;
    const int n0 = blockIdx.x * K2_R;

    for (int r = 0; r < K2_R; ++r) {
        int n = n0 + r;
        for (int d = 0; d < 3; ++d)
            sv[d][r][f] = (n < N) ? v[((size_t)n * 3 + d) * FDIM + f] : 0.f;
    }
    __syncthreads();

    float cacc[K2_R];
    #pragma unroll
    for (int r = 0; r < K2_R; ++r) cacc[r] = 0.f;

    for (int d = 0; d < 3; ++d) {
        float aV[K2_R], aW[K2_R];
        #pragma unroll
        for (int r = 0; r < K2_R; ++r) { aV[r] = 0.f; aW[r] = 0.f; }
        #pragma unroll 4
        for (int a = 0; a < FDIM; ++a) {
            float w0 = Wmix[a * (2 * FDIM) + f];
            float w1 = Wmix[a * (2 * FDIM) + FDIM + f];
            #pragma unroll
            for (int r = 0; r < K2_R; ++r) {
                float t = sv[d][r][a];
                aV[r] = fmaf(t, w0, aV[r]);
                aW[r] = fmaf(t, w1, aW[r]);
            }
        }
        #pragma unroll
        for (int r = 0; r < K2_R; ++r) cacc[r] = fmaf(aV[r], aW[r], cacc[r]);
    }
    for (int r = 0; r < K2_R; ++r) {
        int n = n0 + r;
        if (n < N) ctx[(size_t)n * FDIM + f] = cacc[r];
    }
}

// ---------------------------------------------------------------------------
// Kernel 3: edge gather + segment reduction. Block per atom, seg[] lookup
// (binary search hoisted to k0). Two 128-lane halves over interleaved edges;
// 4 edges (36 loads) in flight per half per iteration. Wij nontemporal
// (streamed once) to keep L2/L3 for the X/V gathers.
// ---------------------------------------------------------------------------
__global__ __launch_bounds__(256) void k3_edges(
    const float* __restrict__ X, const float* __restrict__ V,
    const float* __restrict__ Wij, const float* __restrict__ dir_ij,
    const int* __restrict__ seg, const int* __restrict__ idx_j,
    float* __restrict__ dh, float* __restrict__ dv)
{
    const int n    = blockIdx.x;
    const int tid  = threadIdx.x;
    const int f    = tid & 127;
    const int half = tid >> 7;

    __shared__ int   sj[CHUNK];
    __shared__ float sd[CHUNK][4];
    __shared__ float sacc[4][FDIM];

    const int e0 = seg[n];
    const int e1 = seg[n + 1];

    float adh = 0.f, a0 = 0.f, a1 = 0.f, a2 = 0.f;

#define EDGE_LOAD(kk, W0,W1_,W2_,X0,X1,X2,V0,V1,V2,D0,D1,D2)                   \
    {   const int e_ = base + (kk); const int j_ = sj[(kk)];                   \
        const float* w_ = Wij + (size_t)e_ * F3;                               \
        const float* x_ = X   + (size_t)j_ * F3;                               \
        const float* q_ = V   + (size_t)j_ * F3;                               \
        W0 = __builtin_nontemporal_load(w_ + f);                               \
        W1_ = __builtin_nontemporal_load(w_ + FDIM + f);                       \
        W2_ = __builtin_nontemporal_load(w_ + 2 * FDIM + f);                   \
        X0 = x_[f]; X1 = x_[FDIM + f]; X2 = x_[2 * FDIM + f];                  \
        V0 = q_[f]; V1 = q_[FDIM + f]; V2 = q_[2 * FDIM + f];                  \
        D0 = sd[(kk)][0]; D1 = sd[(kk)][1]; D2 = sd[(kk)][2]; }

#define EDGE_FMA(W0,W1_,W2_,X0,X1,X2,V0,V1,V2,D0,D1,D2)                       \
    {   adh = fmaf(W0, X0, adh);                                               \
        float r_ = W1_ * X1, s_ = W2_ * X2;                                    \
        a0 = fmaf(r_, D0, fmaf(s_, V0, a0));                                   \
        a1 = fmaf(r_, D1, fmaf(s_, V1, a1));                                   \
        a2 = fmaf(r_, D2, fmaf(s_, V2, a2)); }

    for (int base = e0; base < e1; base += CHUNK) {
        const int cnt = (e1 - base < CHUNK) ? (e1 - base) : CHUNK;
        if (tid < cnt) sj[tid] = idx_j[base + tid];
        for (int t = tid; t < 3 * cnt; t += 256)
            sd[t / 3][t % 3] = dir_ij[(size_t)base * 3 + t];
        __syncthreads();

        int k = half;
        for (; k + 6 < cnt; k += 8) {   // 4 edges per half in flight
            float wA0,wA1,wA2,xA0,xA1,xA2,vA0,vA1,vA2,dA0,dA1,dA2;
            float wB0,wB1,wB2,xB0,xB1,xB2,vB0,vB1,vB2,dB0,dB1,dB2;
            float wC0,wC1,wC2,xC0,xC1,xC2,vC0,vC1,vC2,dC0,dC1,dC2;
            float wD0,wD1,wD2,xD0,xD1,xD2,vD0,vD1,vD2,dD0,dD1,dD2;
            EDGE_LOAD(k,     wA0,wA1,wA2,xA0,xA1,xA2,vA0,vA1,vA2,dA0,dA1,dA2)
            EDGE_LOAD(k + 2, wB0,wB1,wB2,xB0,xB1,xB2,vB0,vB1,vB2,dB0,dB1,dB2)
            EDGE_LOAD(k + 4, wC0,wC1,wC2,xC0,xC1,xC2,vC0,vC1,vC2,dC0,dC1,dC2)
            EDGE_LOAD(k + 6, wD0,wD1,wD2,xD0,xD1,xD2,vD0,vD1,vD2,dD0,dD1,dD2)
            EDGE_FMA(wA0,wA1,wA2,xA0,xA1,xA2,vA0,vA1,vA2,dA0,dA1,dA2)
            EDGE_FMA(wB0,wB1,wB2,xB0,xB1,xB2,vB0,vB1,vB2,dB0,dB1,dB2)
            EDGE_FMA(wC0,wC1,wC2,xC0,xC1,xC2,vC0,vC1,vC2,dC0,dC1,dC2)
            EDGE_FMA(wD0,wD1,wD2,xD0,xD1,xD2,vD0,vD1,vD2,dD0,dD1,dD2)
        }
        for (; k < cnt; k += 2) {
            float w0,w1,w2,x0,x1,x2,v0,v1,v2,d0,d1,d2;
            EDGE_LOAD(k, w0,w1,w2,x0,x1,x2,v0,v1,v2,d0,d1,d2)
            EDGE_FMA(w0,w1,w2,x0,x1,x2,v0,v1,v2,d0,d1,d2)
        }
        __syncthreads();
    }
#undef EDGE_LOAD
#undef EDGE_FMA

    if (half == 1) {
        sacc[0][f] = adh; sacc[1][f] = a0; sacc[2][f] = a1; sacc[3][f] = a2;
    }
    __syncthreads();
    if (half == 0) {
        adh += sacc[0][f]; a0 += sacc[1][f]; a1 += sacc[2][f]; a2 += sacc[3][f];
        dh[(size_t)n * FDIM + f]          = adh;
        dv[(size_t)n * F3 + f]            = a0;
        dv[(size_t)n * F3 + FDIM + f]     = a1;
        dv[(size_t)n * F3 + 2 * FDIM + f] = a2;
    }
}

// ---------------------------------------------------------------------------
// Kernel 4: epilogue.
// q  = LN(h + dh@Whr + (dh@Whf)*ctx) * gamma + beta
// mu = (v*(1+dh.Wvr) + dv) / rms
// ---------------------------------------------------------------------------
__device__ inline float block_reduce_sum_128(float val, float* tmp) {
    #pragma unroll
    for (int o = 32; o > 0; o >>= 1) val += __shfl_down(val, o, 64);
    const int tid = threadIdx.x;
    if ((tid & 63) == 0) tmp[tid >> 6] = val;
    __syncthreads();
    float r = tmp[0] + tmp[1];
    __syncthreads();
    return r;
}

__global__ __launch_bounds__(128) void k4_epilogue(
    const float* __restrict__ h,   const float* __restrict__ v,
    const float* __restrict__ dh,  const float* __restrict__ dv,
    const float* __restrict__ ctx,
    const float* __restrict__ Whr, const float* __restrict__ Whf,
    const float* __restrict__ Wvr,
    const float* __restrict__ gamma, const float* __restrict__ beta,
    float* __restrict__ q, float* __restrict__ mu, int N)
{
    __shared__ float sdh[K4_R][FDIM];
    __shared__ float sred[2];
    const int f  = threadIdx.x;
    const int n0 = blockIdx.x * K4_R;

    for (int r = 0; r < K4_R; ++r) {
        int n = n0 + r;
        sdh[r][f] = (n < N) ? dh[(size_t)n * FDIM + f] : 0.f;
    }
    __syncthreads();

    float accR[K4_R], accF[K4_R];
    #pragma unroll
    for (int r = 0; r < K4_R; ++r) { accR[r] = 0.f; accF[r] = 0.f; }
    #pragma unroll 4
    for (int a = 0; a < FDIM; ++a) {
        float wr = Whr[a * FDIM + f];
        float wf = Whf[a * FDIM + f];
        #pragma unroll
        for (int r = 0; r < K4_R; ++r) {
            accR[r] = fmaf(sdh[r][a], wr, accR[r]);
            accF[r] = fmaf(sdh[r][a], wf, accF[r]);
        }
    }

    const float wv = Wvr[f];
    const float g  = gamma[f];
    const float bt = beta[f];

    for (int r = 0; r < K4_R; ++r) {
        int n = n0 + r;
        if (n >= N) break;   // uniform across block

        float s = block_reduce_sum_128(sdh[r][f] * wv, sred);

        float u    = h[(size_t)n * FDIM + f] + accR[r] + accF[r] * ctx[(size_t)n * FDIM + f];
        float mean = block_reduce_sum_128(u, sred) * (1.f / 128.f);
        float dlt  = u - mean;
        float var  = block_reduce_sum_128(dlt * dlt, sred) * (1.f / 128.f);
        q[(size_t)n * FDIM + f] = dlt * rsqrtf(var + 1e-5f) * g + bt;

        float sc = 1.f + s;
        float x0 = fmaf(v[((size_t)n * 3 + 0) * FDIM + f], sc, dv[(size_t)n * F3 + f]);
        float x1 = fmaf(v[((size_t)n * 3 + 1) * FDIM + f], sc, dv[(size_t)n * F3 + FDIM + f]);
        float x2 = fmaf(v[((size_t)n * 3 + 2) * FDIM + f], sc, dv[(size_t)n * F3 + 2 * FDIM + f]);
        float sq  = x0 * x0 + x1 * x1 + x2 * x2;
        float tot = block_reduce_sum_128(sq, sred) * (1.f / 128.f);
        float inv = rsqrtf(tot + 1e-8f);
        mu[((size_t)n * 3 + 0) * FDIM + f] = x0 * inv;
        mu[((size_t)n * 3 + 1) * FDIM + f] = x1 * inv;
        mu[((size_t)n * 3 + 2) * FDIM + f] = x2 * inv;
    }
}

// ---------------------------------------------------------------------------
extern "C" void kernel_launch(void* const* d_in, const int* in_sizes, int n_in,
                              void* d_out, int out_size, void* d_ws, size_t ws_size,
                              hipStream_t stream)
{
    const float* h     = (const float*)d_in[0];
    const float* v     = (const float*)d_in[1];
    const float* H     = (const float*)d_in[2];
    const float* V     = (const float*)d_in[3];
    const float* Wij   = (const float*)d_in[4];
    const float* dir   = (const float*)d_in[5];
    const float* W1    = (const float*)d_in[6];
    const float* b1    = (const float*)d_in[7];
    const float* W2    = (const float*)d_in[8];
    const float* b2    = (const float*)d_in[9];
    const float* Wmix  = (const float*)d_in[10];
    const float* Whr   = (const float*)d_in[11];
    const float* Whf   = (const float*)d_in[12];
    const float* Wvr   = (const float*)d_in[13];
    const float* gamma = (const float*)d_in[14];
    const float* beta  = (const float*)d_in[15];
    const int*   idx_i = (const int*)d_in[16];
    const int*   idx_j = (const int*)d_in[17];

    const int N = in_sizes[0] / FDIM;
    const int E = in_sizes[16];

    float* ws  = (float*)d_ws;
    float* X   = ws;                         // N*384
    float* ctx = X   + (size_t)N * F3;       // N*128
    float* dh  = ctx + (size_t)N * FDIM;     // N*128
    float* dv  = dh  + (size_t)N * FDIM;     // N*384
    int*   seg = (int*)(dv + (size_t)N * F3);// N+1

    float* q   = (float*)d_out;              // N*128
    float* mu  = q + (size_t)N * FDIM;       // N*384

    hipLaunchKernelGGL(k0_seg, dim3((N + 256) / 256), dim3(256), 0, stream,
                       idx_i, seg, E, N);
    hipLaunchKernelGGL(k1_ctxnet, dim3((N + K1_R - 1) / K1_R), dim3(128), 0, stream,
                       H, W1, b1, W2, b2, X, N);
    hipLaunchKernelGGL(k2_ctx, dim3((N + K2_R - 1) / K2_R), dim3(128), 0, stream,
                       v, Wmix, ctx, N);
    hipLaunchKernelGGL(k3_edges, dim3(N), dim3(256), 0, stream,
                       X, V, Wij, dir, seg, idx_j, dh, dv);
    hipLaunchKernelGGL(k4_epilogue, dim3((N + K4_R - 1) / K4_R), dim3(128), 0, stream,
                       h, v, dh, dv, ctx, Whr, Whf, Wvr, gamma, beta, q, mu, N);
}